// Round 5
// baseline (503.328 us; speedup 1.0000x reference)
//
#include <hip/hip_runtime.h>

// Problem constants
#define M_TOT 8192      // 4 * 2048
#define K_TOT 4096      // IN_FEATURES
#define N_TOT 4096      // OUT_FEATURES
#define RANK  64
#define SCALING 0.25f

typedef __bf16 bf16x8 __attribute__((ext_vector_type(8)));
typedef float floatx4 __attribute__((ext_vector_type(4)));
typedef unsigned short ushort8v __attribute__((ext_vector_type(8)));

static __device__ __forceinline__ unsigned short f32_to_bf16(float f) {
  unsigned int u = __float_as_uint(f);
  u += 0x7FFFu + ((u >> 16) & 1u);   // round-to-nearest-even
  return (unsigned short)(u >> 16);
}

// async global->LDS, 16B per lane. LDS dest is wave-uniform base + lane*16.
static __device__ __forceinline__ void async_ld16(const void* g, void* l) {
  __builtin_amdgcn_global_load_lds(
      (const __attribute__((address_space(1))) unsigned int*)g,
      (__attribute__((address_space(3))) unsigned int*)l, 16, 0, 0);
}

// ---------------- kernel 1: convert x fp32 -> bf16 ----------------
__global__ __launch_bounds__(256) void cvt_x_kernel(const float4* __restrict__ x,
                                                    ushort8v* __restrict__ xb) {
  int i = blockIdx.x * 256 + threadIdx.x;   // grid sized exactly: no bounds check
  float4 v0 = x[2 * i];
  float4 v1 = x[2 * i + 1];
  ushort8v o;
  o[0] = f32_to_bf16(v0.x); o[1] = f32_to_bf16(v0.y);
  o[2] = f32_to_bf16(v0.z); o[3] = f32_to_bf16(v0.w);
  o[4] = f32_to_bf16(v1.x); o[5] = f32_to_bf16(v1.y);
  o[6] = f32_to_bf16(v1.z); o[7] = f32_to_bf16(v1.w);
  xb[i] = o;
}

// ---------------- kernel 2: W_eff = bf16(wq*scale + 0.25*B@A) ----------------
// R3 version (kept): 128x128 tile, B staged transposed, 8x8 register blocking,
// all LDS reads are float4.
__global__ __launch_bounds__(256) void build_weff_kernel(
    const int* __restrict__ wq, const float* __restrict__ scale_p,
    const float* __restrict__ A, const float* __restrict__ B,
    unsigned short* __restrict__ Weff) {
  __shared__ __align__(16) float Bts[64][128];   // [r][o] transposed, 32 KB
  __shared__ __align__(16) float As_[64][128];   // [r][k], 32 KB

  const int tid = threadIdx.x;
  const int bo = blockIdx.y * 128;
  const int bk = blockIdx.x * 128;
  const float scale = scale_p[0];

  {
    const int o = tid >> 1;
    const int rh = (tid & 1) * 32;
    const float* gb = B + (size_t)(bo + o) * RANK + rh;
#pragma unroll
    for (int j = 0; j < 8; ++j) {
      float4 v = *(const float4*)(gb + j * 4);
      Bts[rh + j * 4 + 0][o] = v.x;
      Bts[rh + j * 4 + 1][o] = v.y;
      Bts[rh + j * 4 + 2][o] = v.z;
      Bts[rh + j * 4 + 3][o] = v.w;
    }
  }
#pragma unroll
  for (int j = 0; j < 8; ++j) {
    const int ii = j * 1024 + tid * 4;        // float4-aligned flat index
    const int r = ii >> 7, c = ii & 127;
    *(floatx4*)&As_[r][c] = *(const floatx4*)(A + (size_t)r * K_TOT + bk + c);
  }
  __syncthreads();

  const int to = tid >> 4;   // 0..15 -> 8 o-rows
  const int tk = tid & 15;   // 0..15 -> 8 k-cols
  float acc[8][8] = {};
#pragma unroll 4
  for (int r = 0; r < RANK; ++r) {
    floatx4 b0 = *(const floatx4*)&Bts[r][to * 8];
    floatx4 b1 = *(const floatx4*)&Bts[r][to * 8 + 4];
    floatx4 a0 = *(const floatx4*)&As_[r][tk * 8];
    floatx4 a1 = *(const floatx4*)&As_[r][tk * 8 + 4];
    float bv[8] = {b0.x, b0.y, b0.z, b0.w, b1.x, b1.y, b1.z, b1.w};
    float av[8] = {a0.x, a0.y, a0.z, a0.w, a1.x, a1.y, a1.z, a1.w};
#pragma unroll
    for (int a = 0; a < 8; ++a)
#pragma unroll
      for (int b = 0; b < 8; ++b) acc[a][b] += bv[a] * av[b];
  }

#pragma unroll
  for (int a = 0; a < 8; ++a) {
    const int o = bo + to * 8 + a;
    const size_t base = (size_t)o * K_TOT + bk + tk * 8;
    const int4 w0 = *(const int4*)(wq + base);
    const int4 w1 = *(const int4*)(wq + base + 4);
    ushort8v st;
    st[0] = f32_to_bf16((float)w0.x * scale + SCALING * acc[a][0]);
    st[1] = f32_to_bf16((float)w0.y * scale + SCALING * acc[a][1]);
    st[2] = f32_to_bf16((float)w0.z * scale + SCALING * acc[a][2]);
    st[3] = f32_to_bf16((float)w0.w * scale + SCALING * acc[a][3]);
    st[4] = f32_to_bf16((float)w1.x * scale + SCALING * acc[a][4]);
    st[5] = f32_to_bf16((float)w1.y * scale + SCALING * acc[a][5]);
    st[6] = f32_to_bf16((float)w1.z * scale + SCALING * acc[a][6]);
    st[7] = f32_to_bf16((float)w1.w * scale + SCALING * acc[a][7]);
    *(ushort8v*)(Weff + base) = st;
  }
}

// ---------------- kernel 3: main GEMM, out = Xb @ Weff^T ----------------
// R5: faithful m201-style 8-phase schedule — 8 short phases per 2 K-tiles:
// 16 MFMA/phase, 4-8 ds_read/phase, ONE half-tile (2 gld_lds) staged per
// phase (spread, not burst), counted vmcnt(2) only at ph4/ph8 so staged
// loads stay in flight 2-4 phases (~300-600 cyc of latency cover).
// B-frags load once per ks and are reused across both qm phases.
//
// Phase table (group = tiles g(buf0), g+1(buf1); k1=g+1, k2=g+2, k3=g+3):
//  ph1: rd B4(b0,ks0)+A4(b0,qm0,ks0); stage B1(k1)->b1, A0(k1)->b1; MFMA Q00(b0)
//  ph2: rd A4(b0,qm1,ks0);            stage A1(k1)->b1;             MFMA Q10(b0)
//  ph3: rd B4(b0,ks1)+A4(b0,qm0,ks1); no stage;                     MFMA Q01(b0)
//  ph4: rd A4(b0,qm1,ks1);            stage B0(k2)->b0; MFMA Q11(b0); VM(2)
//  ph5-8: same with b0<->b1, k2/k3.
// WAR: every stage target is (a) disjoint from same-phase reads and (b)
// barrier-separated from its region's last reader (last read is drained by
// that phase's lgkmcnt(0) before its end barrier). RAW: VM(2) at ph4 leaves
// only ph4's 2 loads outstanding => tile g+1 fully resident before ph5;
// VM(2) at ph8 => tile g+2 resident before next group's ph1.

template <int QM, int KS>
static __device__ __forceinline__ void mfma_q(floatx4 (&acc)[8][4],
                                              const bf16x8 (&af)[4],
                                              const bf16x8 (&bf)[4][2]) {
#pragma unroll
  for (int i = 0; i < 4; ++i)
#pragma unroll
    for (int j = 0; j < 4; ++j)
      acc[QM * 4 + i][j] = __builtin_amdgcn_mfma_f32_16x16x32_bf16(
          af[i], bf[j][KS], acc[QM * 4 + i][j], 0, 0, 0);
}

__global__ __launch_bounds__(512, 2) void gemm_kernel(
    const unsigned short* __restrict__ Xb,   // [M_TOT][K_TOT] bf16 bits
    const unsigned short* __restrict__ Wb,   // [N_TOT][K_TOT] bf16 bits
    float* __restrict__ out) {               // [M_TOT][N_TOT] fp32
  __shared__ __align__(16) unsigned char smem[131072];

  const int tid = threadIdx.x;
  const int lane = tid & 63;
  const int wave = tid >> 6;   // 0..7
  const int wm = wave >> 2;    // 0..1 -> 128-row half
  const int wn = wave & 3;     // 0..3 -> 64-col quarter

  // XCD-aware swizzle: 512 blocks, 512 % 8 == 0 -> bijective
  const int bid = blockIdx.x;
  const int swz = (bid & 7) * 64 + (bid >> 3);
  const int bM = (swz >> 4) * 256;   // 32 M-blocks
  const int bN = (swz & 15) * 256;   // 16 N-blocks

  // staging source: thread covers 16B; row = tid>>3, chunk = (tid&7)^(row&7)
  const int srow = tid >> 3;                       // 0..63 rows per 8KB issue
  const int scol = ((tid & 7) ^ (srow & 7)) * 8;   // pre-swizzled k offset
  const unsigned short* xs = Xb + (size_t)(bM + srow) * K_TOT + scol;
  const unsigned short* ws = Wb + (size_t)(bN + srow) * K_TOT + scol;

  // ds_read addressing (16-row pattern, proven 0-conflict):
  // frag row = lane&15, logical chunk = ks*4 + (lane>>4), phys = log ^ (lane&7)
  const int rb = (lane & 15) * 128;
  const int c0 = (((lane >> 4) + 0) ^ (lane & 7)) * 16;
  const int c1 = (((lane >> 4) + 4) ^ (lane & 7)) * 16;
  const int aBase = wm * 16384;
  const int bBase = 32768 + wn * 8192;

  floatx4 acc[8][4] = {};
  bf16x8 af[4];      // A frags for current (qm,ks) phase
  bf16x8 bf[4][2];   // B frags per ks, loaded at ks-phase 0, reused at qm1

#define BAR() asm volatile("s_barrier" ::: "memory")
#define WAIT_LGKM0() asm volatile("s_waitcnt lgkmcnt(0)" ::: "memory")
#define WAIT_VM(N) asm volatile("s_waitcnt vmcnt(" #N ")" ::: "memory")
#define SP1() __builtin_amdgcn_s_setprio(1)
#define SP0() __builtin_amdgcn_s_setprio(0)
#define STAGE_A(BUF, H, S, KO)                                              \
  async_ld16(xs + (size_t)((H) * 128 + (S) * 64) * K_TOT + (KO),            \
             smem + (BUF) * 65536 + (H) * 16384 + (S) * 8192 + tid * 16)
#define STAGE_B(BUF, H, S, KO)                                              \
  async_ld16(ws + (size_t)((H) * 128 + (S) * 64) * K_TOT + (KO),            \
             smem + (BUF) * 65536 + 32768 + (H) * 16384 + (S) * 8192 + tid * 16)
#define DSR_A(BUF, QM, II, KS)                                              \
  af[II] = *(const bf16x8*)(smem + (BUF) * 65536 + aBase +                  \
                            ((QM) * 4 + (II)) * 2048 + rb + ((KS) ? c1 : c0))
#define DSR_B(BUF, J, KS)                                                   \
  bf[J][KS] = *(const bf16x8*)(smem + (BUF) * 65536 + bBase +               \
                               (J) * 2048 + rb + ((KS) ? c1 : c0))
#define DSR_A4(BUF, QM, KS)                                                 \
  DSR_A(BUF, QM, 0, KS); DSR_A(BUF, QM, 1, KS);                             \
  DSR_A(BUF, QM, 2, KS); DSR_A(BUF, QM, 3, KS)
#define DSR_B4(BUF, KS)                                                     \
  DSR_B(BUF, 0, KS); DSR_B(BUF, 1, KS); DSR_B(BUF, 2, KS); DSR_B(BUF, 3, KS)
#define CORE(QM, KS)                                                        \
  BAR(); WAIT_LGKM0(); SP1(); mfma_q<QM, KS>(acc, af, bf); SP0()

  // prologue: tile0 all 4 halves -> buf0, B0(tile1) -> buf1; drain once.
  STAGE_A(0, 0, 0, 0); STAGE_A(0, 0, 1, 0);
  STAGE_A(0, 1, 0, 0); STAGE_A(0, 1, 1, 0);
  STAGE_B(0, 0, 0, 0); STAGE_B(0, 0, 1, 0);
  STAGE_B(0, 1, 0, 0); STAGE_B(0, 1, 1, 0);
  STAGE_B(1, 0, 0, 64); STAGE_B(1, 0, 1, 64);
  WAIT_VM(0);
  BAR();

  // 64 K-tiles, 2 per iteration (8 phases). Tail stages (&63) never read.
  for (int kt = 0; kt < 64; kt += 2) {
    const int k1 = ((kt + 1) & 63) * 64;
    const int k2 = ((kt + 2) & 63) * 64;
    const int k3 = ((kt + 3) & 63) * 64;
    // ph1
    DSR_B4(0, 0); DSR_A4(0, 0, 0);
    STAGE_B(1, 1, 0, k1); STAGE_B(1, 1, 1, k1);
    STAGE_A(1, 0, 0, k1); STAGE_A(1, 0, 1, k1);
    CORE(0, 0); BAR();
    // ph2
    DSR_A4(0, 1, 0);
    STAGE_A(1, 1, 0, k1); STAGE_A(1, 1, 1, k1);
    CORE(1, 0); BAR();
    // ph3
    DSR_B4(0, 1); DSR_A4(0, 0, 1);
    CORE(0, 1); BAR();
    // ph4
    DSR_A4(0, 1, 1);
    STAGE_B(0, 0, 0, k2); STAGE_B(0, 0, 1, k2);
    CORE(1, 1); WAIT_VM(2); BAR();
    // ph5
    DSR_B4(1, 0); DSR_A4(1, 0, 0);
    STAGE_B(0, 1, 0, k2); STAGE_B(0, 1, 1, k2);
    STAGE_A(0, 0, 0, k2); STAGE_A(0, 0, 1, k2);
    CORE(0, 0); BAR();
    // ph6
    DSR_A4(1, 1, 0);
    STAGE_A(0, 1, 0, k2); STAGE_A(0, 1, 1, k2);
    CORE(1, 0); BAR();
    // ph7
    DSR_B4(1, 1); DSR_A4(1, 0, 1);
    CORE(0, 1); BAR();
    // ph8
    DSR_A4(1, 1, 1);
    STAGE_B(1, 0, 0, k3); STAGE_B(1, 0, 1, k3);
    CORE(1, 1); WAIT_VM(2); BAR();
  }
  WAIT_VM(0);   // drain tail stages before workgroup exit

  // epilogue: C(i,j,r): row = bM+wm*128+i*16+(lane>>4)*4+r, col = bN+wn*64+j*16+(lane&15)
  const int row0 = bM + wm * 128 + ((lane >> 4) << 2);
  const int col0 = bN + wn * 64 + (lane & 15);
#pragma unroll
  for (int i = 0; i < 8; ++i) {
#pragma unroll
    for (int j = 0; j < 4; ++j) {
#pragma unroll
      for (int r = 0; r < 4; ++r) {
        out[(size_t)(row0 + i * 16 + r) * N_TOT + (col0 + j * 16)] = acc[i][j][r];
      }
    }
  }
#undef BAR
#undef WAIT_LGKM0
#undef WAIT_VM
#undef SP1
#undef SP0
#undef STAGE_A
#undef STAGE_B
#undef DSR_A
#undef DSR_B
#undef DSR_A4
#undef DSR_B4
#undef CORE
}

extern "C" void kernel_launch(void* const* d_in, const int* in_sizes, int n_in,
                              void* d_out, int out_size, void* d_ws, size_t ws_size,
                              hipStream_t stream) {
  const float* x      = (const float*)d_in[0];   // [4,2048,4096] fp32
  const int*   wq     = (const int*)d_in[1];     // [4096,4096] int
  const float* wscale = (const float*)d_in[2];   // [1] fp32
  const float* lora_A = (const float*)d_in[3];   // [64,4096] fp32
  const float* lora_B = (const float*)d_in[4];   // [4096,64] fp32
  float* out = (float*)d_out;

  unsigned short* xb   = (unsigned short*)d_ws;
  unsigned short* weff = (unsigned short*)((char*)d_ws + (size_t)M_TOT * K_TOT * 2);

  cvt_x_kernel<<<16384, 256, 0, stream>>>((const float4*)x, (ushort8v*)xb);
  build_weff_kernel<<<dim3(K_TOT / 128, N_TOT / 128), 256, 0, stream>>>(
      wq, wscale, lora_A, lora_B, weff);
  gemm_kernel<<<512, 512, 0, stream>>>(xb, weff, out);
}